// Round 3
// baseline (572.944 us; speedup 1.0000x reference)
//
#include <hip/hip_runtime.h>

// EuclideanCodebook via bf16x3-split MFMA distance + compacted exact fp32 rescue.
// x: [N=32768][256] f32, embedding_sum: [K=2048][256] f32, usage: [K] f32
// out: quantized [N*256] f32, codes [N] f32

#define EPSV 1e-5f
#define DDIM 256
#define TAU  0.05f
#define BM   128     // rows per block
#define BCL  128     // clusters per tile
#define NCT  8       // cluster tiles per half (1024/128)
#define CHN  12      // inner chunks (768 = 12*64)

typedef __attribute__((ext_vector_type(8))) short bf16x8;
typedef __attribute__((ext_vector_type(4))) float f32x4;
typedef unsigned short u16;

__device__ __forceinline__ u16 f2bf(float f) {
    unsigned u = __builtin_bit_cast(unsigned, f);
    u = (u + 0x7fffu + ((u >> 16) & 1u)) >> 16;
    return (u16)u;
}
__device__ __forceinline__ float bf2f(u16 h) {
    unsigned u = ((unsigned)h) << 16;
    return __builtin_bit_cast(float, u);
}

// ---------------- prep_e: emb, e_hi, e_lo, ||e||^2; zero rescue counter -----
__global__ void prep_e(const float* __restrict__ esum,
                       const float* __restrict__ usage,
                       float* __restrict__ emb,     // [K][256] f32
                       u16* __restrict__ ehi,       // [K][256]
                       u16* __restrict__ elo,       // [K][256]
                       float* __restrict__ enorm2,  // [K]
                       int* __restrict__ counter,
                       int K) {
    if (blockIdx.x == 0 && threadIdx.x == 0) *counter = 0;
    const int k = blockIdx.x;
    const int d = threadIdx.x;                 // 256 threads
    const float u = fmaxf(usage[k], EPSV);
    const float e = esum[k * DDIM + d] / u;
    emb[k * DDIM + d] = e;
    const u16 h = f2bf(e);
    ehi[k * DDIM + d] = h;
    elo[k * DDIM + d] = f2bf(e - bf2f(h));

    float s = e * e;
    #pragma unroll
    for (int off = 32; off > 0; off >>= 1) s += __shfl_down(s, off, 64);
    __shared__ float ws[4];
    if ((threadIdx.x & 63) == 0) ws[threadIdx.x >> 6] = s;
    __syncthreads();
    if (threadIdx.x == 0) enorm2[k] = ws[0] + ws[1] + ws[2] + ws[3];
}

// ---------------- prep_x: x_hi, x_lo ----------------------------------------
__global__ void prep_x(const float* __restrict__ x,
                       u16* __restrict__ xhi, u16* __restrict__ xlo) {
    const int n = blockIdx.x * 4 + (threadIdx.x >> 6);
    const int l = threadIdx.x & 63;
    const float4 v = *(const float4*)&x[(size_t)n * DDIM + l * 4];
    ushort4 h, lo;
    h.x = f2bf(v.x); lo.x = f2bf(v.x - bf2f(h.x));
    h.y = f2bf(v.y); lo.y = f2bf(v.y - bf2f(h.y));
    h.z = f2bf(v.z); lo.z = f2bf(v.z - bf2f(h.z));
    h.w = f2bf(v.w); lo.w = f2bf(v.w - bf2f(h.w));
    *(ushort4*)&xhi[(size_t)n * DDIM + l * 4] = h;
    *(ushort4*)&xlo[(size_t)n * DDIM + l * 4] = lo;
}

// ---------------- main: MFMA distance + running (min1, idx, min2) ----------
__global__ __launch_bounds__(256, 2) void vq_mfma(
        const u16* __restrict__ xhi, const u16* __restrict__ xlo,
        const u16* __restrict__ ehi, const u16* __restrict__ elo,
        const float* __restrict__ enorm2,
        float* __restrict__ pm1, int* __restrict__ pi1,
        float* __restrict__ pm2, int N) {
    __shared__ u16 Als[BM * 64];    // 16 KB
    __shared__ u16 Bls[BCL * 64];   // 16 KB

    const int tid = threadIdx.x;
    const int l   = tid & 63;
    const int w   = tid >> 6;            // wave 0..3
    const int wr  = w >> 1, wc = w & 1;  // 2x2 wave grid (64x64 each)
    const int rowblk = blockIdx.x >> 1;
    const int half   = blockIdx.x & 1;
    const int n0     = rowblk * BM;
    const int cbase  = half * 1024;

    float m1[4][4], m2[4][4];
    int   i1[4][4];
    #pragma unroll
    for (int a = 0; a < 4; ++a)
        #pragma unroll
        for (int b = 0; b < 4; ++b) { m1[a][b] = 3.0e38f; m2[a][b] = 3.0e38f; i1[a][b] = 0; }

    for (int ct = 0; ct < NCT; ++ct) {
        const int c0 = cbase + ct * BCL;
        f32x4 acc[4][4];
        #pragma unroll
        for (int a = 0; a < 4; ++a)
            #pragma unroll
            for (int b = 0; b < 4; ++b) acc[a][b] = (f32x4){0.f, 0.f, 0.f, 0.f};

        for (int ch = 0; ch < CHN; ++ch) {
            // inner chunk ch of 768: A = [xhi | xhi | xlo], B = [ehi | elo | ehi]
            const u16* asrc = (ch < 8) ? xhi : xlo;
            const u16* bsrc = (ch < 4) ? ehi : ((ch < 8) ? elo : ehi);
            const int colof = (ch & 3) * 64;

            __syncthreads();
            #pragma unroll
            for (int j = 0; j < 4; ++j) {
                const int r = (w * 4 + j) * 8 + (l >> 3);
                const u16* ga = asrc + (size_t)(n0 + r) * DDIM + colof + (l & 7) * 8;
                __builtin_amdgcn_global_load_lds(
                    (const __attribute__((address_space(1))) void*)ga,
                    (__attribute__((address_space(3))) void*)((char*)Als + (w * 4 + j) * 1024),
                    16, 0, 0);
            }
            #pragma unroll
            for (int j = 0; j < 4; ++j) {
                const int r = (w * 4 + j) * 8 + (l >> 3);
                const u16* gb = bsrc + (size_t)(c0 + r) * DDIM + colof + (l & 7) * 8;
                __builtin_amdgcn_global_load_lds(
                    (const __attribute__((address_space(1))) void*)gb,
                    (__attribute__((address_space(3))) void*)((char*)Bls + (w * 4 + j) * 1024),
                    16, 0, 0);
            }
            __syncthreads();

            #pragma unroll
            for (int ks = 0; ks < 2; ++ks) {
                bf16x8 af[4], bfr[4];
                #pragma unroll
                for (int f = 0; f < 4; ++f) {
                    const int arow = wr * 64 + f * 16 + (l & 15);
                    af[f] = *(const bf16x8*)((const char*)Als + arow * 128 + ks * 64 + (l >> 4) * 16);
                    const int brow = wc * 64 + f * 16 + (l & 15);
                    bfr[f] = *(const bf16x8*)((const char*)Bls + brow * 128 + ks * 64 + (l >> 4) * 16);
                }
                #pragma unroll
                for (int fm = 0; fm < 4; ++fm)
                    #pragma unroll
                    for (int fn = 0; fn < 4; ++fn)
                        acc[fm][fn] = __builtin_amdgcn_mfma_f32_16x16x32_bf16(
                            af[fm], bfr[fn], acc[fm][fn], 0, 0, 0);
            }
        }

        // fold tile distances into running (min1, idx, min2); cols ascend in fn
        #pragma unroll
        for (int fn = 0; fn < 4; ++fn) {
            const int k = c0 + wc * 64 + fn * 16 + (l & 15);
            const float en = enorm2[k];
            #pragma unroll
            for (int fm = 0; fm < 4; ++fm)
                #pragma unroll
                for (int i = 0; i < 4; ++i) {
                    const float s = fmaf(-2.0f, acc[fm][fn][i], en);
                    const bool lt1 = s < m1[fm][i];
                    const bool lt2 = s < m2[fm][i];
                    m2[fm][i] = lt1 ? m1[fm][i] : (lt2 ? s : m2[fm][i]);
                    i1[fm][i] = lt1 ? k : i1[fm][i];
                    m1[fm][i] = lt1 ? s : m1[fm][i];
                }
        }
    }

    // reduce across the 16 lanes (l&15) that share rows
    #pragma unroll
    for (int fm = 0; fm < 4; ++fm)
        #pragma unroll
        for (int i = 0; i < 4; ++i) {
            float a1 = m1[fm][i], a2 = m2[fm][i];
            int ai = i1[fm][i];
            #pragma unroll
            for (int mask = 1; mask < 16; mask <<= 1) {
                const float b1 = __shfl_xor(a1, mask, 64);
                const int   bi = __shfl_xor(ai, mask, 64);
                const float b2 = __shfl_xor(a2, mask, 64);
                if (b1 < a1 || (b1 == a1 && bi < ai)) {
                    a2 = fminf(a1, fminf(a2, b2)); a1 = b1; ai = bi;
                } else {
                    a2 = fminf(b1, fminf(a2, b2));
                }
            }
            m1[fm][i] = a1; i1[fm][i] = ai; m2[fm][i] = a2;
        }

    // merge the two wave-columns via LDS, write per-(half,row) partials
    __syncthreads();
    float* Sm1 = (float*)Als;
    int*   Si1 = (int*)((char*)Als + 512);
    float* Sm2 = (float*)((char*)Als + 1024);
    if (wc == 0 && (l & 15) == 0) {
        #pragma unroll
        for (int fm = 0; fm < 4; ++fm)
            #pragma unroll
            for (int i = 0; i < 4; ++i) {
                const int r = wr * 64 + fm * 16 + (l >> 4) * 4 + i;
                Sm1[r] = m1[fm][i]; Si1[r] = i1[fm][i]; Sm2[r] = m2[fm][i];
            }
    }
    __syncthreads();
    if (wc == 1 && (l & 15) == 0) {
        #pragma unroll
        for (int fm = 0; fm < 4; ++fm)
            #pragma unroll
            for (int i = 0; i < 4; ++i) {
                const int r = wr * 64 + fm * 16 + (l >> 4) * 4 + i;
                const float b1 = Sm1[r], b2 = Sm2[r];
                const int   bi = Si1[r];
                float a1 = m1[fm][i], a2 = m2[fm][i];
                int   ai = i1[fm][i];
                float M1, M2; int MI;
                if (b1 < a1 || (b1 == a1 && bi < ai)) {
                    M1 = b1; MI = bi; M2 = fminf(a1, fminf(a2, b2));
                } else {
                    M1 = a1; MI = ai; M2 = fminf(b1, fminf(a2, b2));
                }
                const int n = n0 + r;
                pm1[(size_t)half * N + n] = M1;
                pi1[(size_t)half * N + n] = MI;
                pm2[(size_t)half * N + n] = M2;
            }
    }
}

// ---------------- combine halves -> codes + compacted rescue list -----------
__global__ void combine(const float* __restrict__ pm1, const int* __restrict__ pi1,
                        const float* __restrict__ pm2,
                        float* __restrict__ codes_f, int* __restrict__ codes_i,
                        int* __restrict__ list, int* __restrict__ counter, int N) {
    const int n = blockIdx.x * 256 + threadIdx.x;
    const float a1 = pm1[n], a2 = pm2[n];
    const int   ai = pi1[n];
    const float b1 = pm1[(size_t)N + n], b2 = pm2[(size_t)N + n];
    const int   bi = pi1[(size_t)N + n];
    float M1, M2; int MI;
    if (b1 < a1 || (b1 == a1 && bi < ai)) {
        M1 = b1; MI = bi; M2 = fminf(a1, fminf(a2, b2));
    } else {
        M1 = a1; MI = ai; M2 = fminf(b1, fminf(a2, b2));
    }
    codes_i[n] = MI;
    codes_f[n] = (float)MI;
    if (M2 - M1 < TAU) {
        const int idx = atomicAdd(counter, 1);
        list[idx] = n;
    }
}

// ---------------- rescue_c: exact fp32 re-score of compacted rows -----------
// 64 blocks x 256 threads; block strides the compact list. Per row: 4 waves
// split K (512 clusters each), lanes split D (lane l owns x[4l..4l+3]); each
// cluster is one coalesced 1KB wave-load of emb[k][:] (L2-resident).
__global__ __launch_bounds__(256) void rescue_c(
        const float* __restrict__ x, const float* __restrict__ emb,
        const float* __restrict__ enorm2,
        const int* __restrict__ list, const int* __restrict__ counter,
        float* __restrict__ codes_f, int* __restrict__ codes_i, int K) {
    const int w = threadIdx.x >> 6;
    const int l = threadIdx.x & 63;
    __shared__ float red_d[4];
    __shared__ int   red_k[4];
    const int cnt = *counter;
    const int kpw = K / 4;                      // 512 clusters per wave

    for (int i = blockIdx.x; i < cnt; i += gridDim.x) {
        const int n = list[i];
        const float4 xr = *(const float4*)&x[(size_t)n * DDIM + l * 4];
        float best = 3.0e38f;
        int   bk = 0;
        #pragma unroll 4
        for (int kk = 0; kk < kpw; ++kk) {
            const int k = w * kpw + kk;
            const float4 e = *(const float4*)&emb[(size_t)k * DDIM + l * 4];
            float p = xr.x * e.x;
            p = fmaf(xr.y, e.y, p);
            p = fmaf(xr.z, e.z, p);
            p = fmaf(xr.w, e.w, p);
            #pragma unroll
            for (int m = 32; m > 0; m >>= 1) p += __shfl_xor(p, m, 64);
            const float s = fmaf(-2.0f, p, enorm2[k]);
            if (s < best) { best = s; bk = k; }   // identical across lanes
        }
        if (l == 0) { red_d[w] = best; red_k[w] = bk; }
        __syncthreads();
        if (threadIdx.x == 0) {
            float B = red_d[0]; int BI = red_k[0];
            #pragma unroll
            for (int j = 1; j < 4; ++j)
                if (red_d[j] < B || (red_d[j] == B && red_k[j] < BI)) {
                    B = red_d[j]; BI = red_k[j];
                }
            codes_i[n] = BI;
            codes_f[n] = (float)BI;
        }
        __syncthreads();
    }
}

// ---------------- gather: quantized[n] = emb[code[n]] -----------------------
__global__ void gather_q(const float* __restrict__ emb,
                         const int* __restrict__ codes,
                         float* __restrict__ qout) {
    const int n = blockIdx.x * 4 + (threadIdx.x >> 6);
    const int c = threadIdx.x & 63;
    const int k = codes[n];
    *(float4*)&qout[(size_t)n * DDIM + c * 4] =
        *(const float4*)&emb[(size_t)k * DDIM + c * 4];
}

extern "C" void kernel_launch(void* const* d_in, const int* in_sizes, int n_in,
                              void* d_out, int out_size, void* d_ws, size_t ws_size,
                              hipStream_t stream) {
    const float* x     = (const float*)d_in[0];
    const float* esum  = (const float*)d_in[1];
    const float* usage = (const float*)d_in[2];
    const int K = in_sizes[2];                 // 2048
    const int N = in_sizes[0] / DDIM;          // 32768

    // workspace layout
    char* p = (char*)d_ws;
    float* emb     = (float*)p;                p += (size_t)K * DDIM * 4;   // 2 MB
    float* enorm2  = (float*)p;                p += (size_t)K * 4;
    float* pm1     = (float*)p;                p += (size_t)2 * N * 4;
    float* pm2     = (float*)p;                p += (size_t)2 * N * 4;
    int*   pi1     = (int*)p;                  p += (size_t)2 * N * 4;
    int*   codes_i = (int*)p;                  p += (size_t)N * 4;
    int*   list    = (int*)p;                  p += (size_t)N * 4;
    int*   counter = (int*)p;                  p += 256;                     // padded
    u16*   xhi     = (u16*)p;                  p += (size_t)N * DDIM * 2;   // 16 MB
    u16*   xlo     = (u16*)p;                  p += (size_t)N * DDIM * 2;   // 16 MB
    u16*   ehi     = (u16*)p;                  p += (size_t)K * DDIM * 2;   // 1 MB
    u16*   elo     = (u16*)p;                  p += (size_t)K * DDIM * 2;   // 1 MB

    float* qout    = (float*)d_out;            // N*256
    float* codes_f = qout + (size_t)N * DDIM;  // N

    prep_e<<<K, 256, 0, stream>>>(esum, usage, emb, ehi, elo, enorm2, counter, K);
    prep_x<<<N / 4, 256, 0, stream>>>(x, xhi, xlo);
    vq_mfma<<<(N / BM) * 2, 256, 0, stream>>>(xhi, xlo, ehi, elo, enorm2,
                                              pm1, pi1, pm2, N);
    combine<<<N / 256, 256, 0, stream>>>(pm1, pi1, pm2, codes_f, codes_i,
                                         list, counter, N);
    rescue_c<<<64, 256, 0, stream>>>(x, emb, enorm2, list, counter,
                                     codes_f, codes_i, K);
    gather_q<<<N / 4, 256, 0, stream>>>(emb, codes_i, qout);
}

// Round 4
// 181.501 us; speedup vs baseline: 3.1567x; 3.1567x over previous
//
#include <hip/hip_runtime.h>

// EuclideanCodebook: bf16 (hi-only) MFMA approx distance + top-2 margin flag
// + batched exact fp32 rescue over a d-major codebook.
// x: [N=32768][256] f32, embedding_sum: [K=2048][256] f32, usage: [K] f32
// out: quantized [N*256] f32, codes [N] f32

#define EPSV 1e-5f
#define DDIM 256
#define TAU  1.0f
#define BM   128     // rows per block
#define BCL  128     // clusters per tile
#define NCT  8       // cluster tiles per half (1024/128)
#define RPB  8       // rescue rows per block

typedef __attribute__((ext_vector_type(8))) short bf16x8;
typedef __attribute__((ext_vector_type(4))) float f32x4;
typedef unsigned short u16;

__device__ __forceinline__ u16 f2bf(float f) {
    unsigned u = __builtin_bit_cast(unsigned, f);
    u = (u + 0x7fffu + ((u >> 16) & 1u)) >> 16;
    return (u16)u;
}

// ---------------- prep_e: emb, emb_t, e_hi, ||e||^2; zero counter -----------
__global__ void prep_e(const float* __restrict__ esum,
                       const float* __restrict__ usage,
                       float* __restrict__ emb,     // [K][256] f32
                       float* __restrict__ emb_t,   // [256][K] f32
                       u16* __restrict__ ehi,       // [K][256]
                       float* __restrict__ enorm2,  // [K]
                       int* __restrict__ counter,
                       int K) {
    if (blockIdx.x == 0 && threadIdx.x == 0) *counter = 0;
    const int k = blockIdx.x;
    const int d = threadIdx.x;                 // 256 threads
    const float u = fmaxf(usage[k], EPSV);
    const float e = esum[k * DDIM + d] / u;
    emb[k * DDIM + d] = e;
    emb_t[(size_t)d * K + k] = e;
    ehi[k * DDIM + d] = f2bf(e);

    float s = e * e;
    #pragma unroll
    for (int off = 32; off > 0; off >>= 1) s += __shfl_down(s, off, 64);
    __shared__ float ws[4];
    if ((threadIdx.x & 63) == 0) ws[threadIdx.x >> 6] = s;
    __syncthreads();
    if (threadIdx.x == 0) enorm2[k] = ws[0] + ws[1] + ws[2] + ws[3];
}

// ---------------- prep_x: x_hi ----------------------------------------------
__global__ void prep_x(const float* __restrict__ x, u16* __restrict__ xhi) {
    const int n = blockIdx.x * 4 + (threadIdx.x >> 6);
    const int l = threadIdx.x & 63;
    const float4 v = *(const float4*)&x[(size_t)n * DDIM + l * 4];
    ushort4 h;
    h.x = f2bf(v.x); h.y = f2bf(v.y); h.z = f2bf(v.z); h.w = f2bf(v.w);
    *(ushort4*)&xhi[(size_t)n * DDIM + l * 4] = h;
}

// ---------------- main: MFMA approx distance + running (min1, idx, min2) ----
__global__ __launch_bounds__(256, 2) void vq_mfma(
        const u16* __restrict__ xhi, const u16* __restrict__ ehi,
        const float* __restrict__ enorm2,
        float* __restrict__ pm1, int* __restrict__ pi1,
        float* __restrict__ pm2, int N) {
    __shared__ u16 Als[BM * 64];    // 16 KB
    __shared__ u16 Bls[BCL * 64];   // 16 KB

    const int tid = threadIdx.x;
    const int l   = tid & 63;
    const int w   = tid >> 6;            // wave 0..3
    const int wr  = w >> 1, wc = w & 1;  // 2x2 wave grid (64x64 each)
    const int rowblk = blockIdx.x >> 1;
    const int half   = blockIdx.x & 1;
    const int n0     = rowblk * BM;
    const int cbase  = half * 1024;

    float m1[4][4], m2[4][4];
    int   i1[4][4];
    #pragma unroll
    for (int a = 0; a < 4; ++a)
        #pragma unroll
        for (int b = 0; b < 4; ++b) { m1[a][b] = 3.0e38f; m2[a][b] = 3.0e38f; i1[a][b] = 0; }

    for (int ct = 0; ct < NCT; ++ct) {
        const int c0 = cbase + ct * BCL;
        f32x4 acc[4][4];
        #pragma unroll
        for (int a = 0; a < 4; ++a)
            #pragma unroll
            for (int b = 0; b < 4; ++b) acc[a][b] = (f32x4){0.f, 0.f, 0.f, 0.f};

        for (int ch = 0; ch < 4; ++ch) {       // 256 = 4 x 64 inner dims
            const int colof = ch * 64;

            __syncthreads();
            #pragma unroll
            for (int j = 0; j < 4; ++j) {
                const int r = (w * 4 + j) * 8 + (l >> 3);
                const u16* ga = xhi + (size_t)(n0 + r) * DDIM + colof + (l & 7) * 8;
                __builtin_amdgcn_global_load_lds(
                    (const __attribute__((address_space(1))) void*)ga,
                    (__attribute__((address_space(3))) void*)((char*)Als + (w * 4 + j) * 1024),
                    16, 0, 0);
            }
            #pragma unroll
            for (int j = 0; j < 4; ++j) {
                const int r = (w * 4 + j) * 8 + (l >> 3);
                const u16* gb = ehi + (size_t)(c0 + r) * DDIM + colof + (l & 7) * 8;
                __builtin_amdgcn_global_load_lds(
                    (const __attribute__((address_space(1))) void*)gb,
                    (__attribute__((address_space(3))) void*)((char*)Bls + (w * 4 + j) * 1024),
                    16, 0, 0);
            }
            __syncthreads();

            #pragma unroll
            for (int ks = 0; ks < 2; ++ks) {
                bf16x8 af[4], bfr[4];
                #pragma unroll
                for (int f = 0; f < 4; ++f) {
                    const int arow = wr * 64 + f * 16 + (l & 15);
                    af[f] = *(const bf16x8*)((const char*)Als + arow * 128 + ks * 64 + (l >> 4) * 16);
                    const int brow = wc * 64 + f * 16 + (l & 15);
                    bfr[f] = *(const bf16x8*)((const char*)Bls + brow * 128 + ks * 64 + (l >> 4) * 16);
                }
                #pragma unroll
                for (int fm = 0; fm < 4; ++fm)
                    #pragma unroll
                    for (int fn = 0; fn < 4; ++fn)
                        acc[fm][fn] = __builtin_amdgcn_mfma_f32_16x16x32_bf16(
                            af[fm], bfr[fn], acc[fm][fn], 0, 0, 0);
            }
        }

        // fold tile distances into running (min1, idx, min2); k ascending
        #pragma unroll
        for (int fn = 0; fn < 4; ++fn) {
            const int k = c0 + wc * 64 + fn * 16 + (l & 15);
            const float en = enorm2[k];
            #pragma unroll
            for (int fm = 0; fm < 4; ++fm)
                #pragma unroll
                for (int i = 0; i < 4; ++i) {
                    const float s = fmaf(-2.0f, acc[fm][fn][i], en);
                    const bool lt1 = s < m1[fm][i];
                    m2[fm][i] = fminf(m2[fm][i], fmaxf(s, m1[fm][i]));
                    i1[fm][i] = lt1 ? k : i1[fm][i];
                    m1[fm][i] = fminf(m1[fm][i], s);
                }
        }
    }

    // reduce across the 16 lanes (l&15) that share rows
    #pragma unroll
    for (int fm = 0; fm < 4; ++fm)
        #pragma unroll
        for (int i = 0; i < 4; ++i) {
            float a1 = m1[fm][i], a2 = m2[fm][i];
            int ai = i1[fm][i];
            #pragma unroll
            for (int mask = 1; mask < 16; mask <<= 1) {
                const float b1 = __shfl_xor(a1, mask, 64);
                const int   bi = __shfl_xor(ai, mask, 64);
                const float b2 = __shfl_xor(a2, mask, 64);
                if (b1 < a1 || (b1 == a1 && bi < ai)) {
                    a2 = fminf(a1, fminf(a2, b2)); a1 = b1; ai = bi;
                } else {
                    a2 = fminf(b1, fminf(a2, b2));
                }
            }
            m1[fm][i] = a1; i1[fm][i] = ai; m2[fm][i] = a2;
        }

    // merge the two wave-columns via LDS, write per-(half,row) partials
    __syncthreads();
    float* Sm1 = (float*)Als;
    int*   Si1 = (int*)((char*)Als + 512);
    float* Sm2 = (float*)((char*)Als + 1024);
    if (wc == 0 && (l & 15) == 0) {
        #pragma unroll
        for (int fm = 0; fm < 4; ++fm)
            #pragma unroll
            for (int i = 0; i < 4; ++i) {
                const int r = wr * 64 + fm * 16 + (l >> 4) * 4 + i;
                Sm1[r] = m1[fm][i]; Si1[r] = i1[fm][i]; Sm2[r] = m2[fm][i];
            }
    }
    __syncthreads();
    if (wc == 1 && (l & 15) == 0) {
        #pragma unroll
        for (int fm = 0; fm < 4; ++fm)
            #pragma unroll
            for (int i = 0; i < 4; ++i) {
                const int r = wr * 64 + fm * 16 + (l >> 4) * 4 + i;
                const float b1 = Sm1[r], b2 = Sm2[r];
                const int   bi = Si1[r];
                float a1 = m1[fm][i], a2 = m2[fm][i];
                int   ai = i1[fm][i];
                float M1, M2; int MI;
                if (b1 < a1 || (b1 == a1 && bi < ai)) {
                    M1 = b1; MI = bi; M2 = fminf(a1, fminf(a2, b2));
                } else {
                    M1 = a1; MI = ai; M2 = fminf(b1, fminf(a2, b2));
                }
                const int n = n0 + r;
                pm1[(size_t)half * N + n] = M1;
                pi1[(size_t)half * N + n] = MI;
                pm2[(size_t)half * N + n] = M2;
            }
    }
}

// ---------------- combine halves -> codes + compacted rescue list -----------
__global__ void combine(const float* __restrict__ pm1, const int* __restrict__ pi1,
                        const float* __restrict__ pm2,
                        float* __restrict__ codes_f, int* __restrict__ codes_i,
                        int* __restrict__ list, int* __restrict__ counter, int N) {
    const int n = blockIdx.x * 256 + threadIdx.x;
    const float a1 = pm1[n], a2 = pm2[n];
    const int   ai = pi1[n];
    const float b1 = pm1[(size_t)N + n], b2 = pm2[(size_t)N + n];
    const int   bi = pi1[(size_t)N + n];
    float M1, M2; int MI;
    if (b1 < a1 || (b1 == a1 && bi < ai)) {
        M1 = b1; MI = bi; M2 = fminf(a1, fminf(a2, b2));
    } else {
        M1 = a1; MI = ai; M2 = fminf(b1, fminf(a2, b2));
    }
    codes_i[n] = MI;
    codes_f[n] = (float)MI;
    if (M2 - M1 < TAU) {
        const int idx = atomicAdd(counter, 1);
        list[idx] = n;
    }
}

// ---------------- rescue_c: exact fp32 re-score, 8 rows/block, coalesced ----
// thread t owns clusters {4t..4t+3, K/2+4t..K/2+4t+3}; emb_t is d-major so
// every load is coalesced; 64 independent fma chains; no cross-lane ops in
// the inner loop.
__global__ __launch_bounds__(256) void rescue_c(
        const float* __restrict__ x, const float* __restrict__ emb_t,
        const float* __restrict__ enorm2,
        const int* __restrict__ list, const int* __restrict__ counter,
        float* __restrict__ codes_f, int* __restrict__ codes_i, int K) {
    __shared__ float xs[RPB][DDIM];   // 8 KB
    __shared__ float rbd[RPB][4];
    __shared__ int   rbk[RPB][4];
    const int t = threadIdx.x;
    const int w = t >> 6, l = t & 63;
    const int cnt = *counter;
    const int nblk = (cnt + RPB - 1) / RPB;
    const int koff = K >> 1;          // 1024

    for (int b = blockIdx.x; b < nblk; b += gridDim.x) {
        const int base = b * RPB;
        int rows[RPB];
        #pragma unroll
        for (int r = 0; r < RPB; ++r) {
            const int idx = base + r;
            rows[r] = list[idx < cnt ? idx : base];   // clamp -> duplicate row0
        }
        __syncthreads();
        #pragma unroll
        for (int r = 0; r < RPB; ++r)
            xs[r][t] = x[(size_t)rows[r] * DDIM + t];
        __syncthreads();

        float acc[2][RPB][4];
        #pragma unroll
        for (int j = 0; j < 2; ++j)
            #pragma unroll
            for (int r = 0; r < RPB; ++r)
                #pragma unroll
                for (int c = 0; c < 4; ++c) acc[j][r][c] = 0.f;

        #pragma unroll 2
        for (int d = 0; d < DDIM; ++d) {
            const float4 e0 = *(const float4*)&emb_t[(size_t)d * K + 4 * t];
            const float4 e1 = *(const float4*)&emb_t[(size_t)d * K + koff + 4 * t];
            #pragma unroll
            for (int r = 0; r < RPB; ++r) {
                const float xv = xs[r][d];
                acc[0][r][0] = fmaf(xv, e0.x, acc[0][r][0]);
                acc[0][r][1] = fmaf(xv, e0.y, acc[0][r][1]);
                acc[0][r][2] = fmaf(xv, e0.z, acc[0][r][2]);
                acc[0][r][3] = fmaf(xv, e0.w, acc[0][r][3]);
                acc[1][r][0] = fmaf(xv, e1.x, acc[1][r][0]);
                acc[1][r][1] = fmaf(xv, e1.y, acc[1][r][1]);
                acc[1][r][2] = fmaf(xv, e1.z, acc[1][r][2]);
                acc[1][r][3] = fmaf(xv, e1.w, acc[1][r][3]);
            }
        }

        #pragma unroll
        for (int r = 0; r < RPB; ++r) {
            float bd = 3.0e38f; int bk = 0;
            #pragma unroll
            for (int j = 0; j < 2; ++j)
                #pragma unroll
                for (int c = 0; c < 4; ++c) {
                    const int k = j * koff + 4 * t + c;   // ascending per thread
                    const float s = fmaf(-2.0f, acc[j][r][c], enorm2[k]);
                    if (s < bd) { bd = s; bk = k; }
                }
            #pragma unroll
            for (int m = 1; m < 64; m <<= 1) {
                const float od = __shfl_xor(bd, m, 64);
                const int   ok = __shfl_xor(bk, m, 64);
                if (od < bd || (od == bd && ok < bk)) { bd = od; bk = ok; }
            }
            if (l == 0) { rbd[r][w] = bd; rbk[r][w] = bk; }
        }
        __syncthreads();
        if (t < RPB) {
            float B = rbd[t][0]; int BI = rbk[t][0];
            #pragma unroll
            for (int j = 1; j < 4; ++j)
                if (rbd[t][j] < B || (rbd[t][j] == B && rbk[t][j] < BI)) {
                    B = rbd[t][j]; BI = rbk[t][j];
                }
            codes_i[rows[t]] = BI;
            codes_f[rows[t]] = (float)BI;
        }
        __syncthreads();
    }
}

// ---------------- gather: quantized[n] = emb[code[n]] -----------------------
__global__ void gather_q(const float* __restrict__ emb,
                         const int* __restrict__ codes,
                         float* __restrict__ qout) {
    const int n = blockIdx.x * 4 + (threadIdx.x >> 6);
    const int c = threadIdx.x & 63;
    const int k = codes[n];
    *(float4*)&qout[(size_t)n * DDIM + c * 4] =
        *(const float4*)&emb[(size_t)k * DDIM + c * 4];
}

extern "C" void kernel_launch(void* const* d_in, const int* in_sizes, int n_in,
                              void* d_out, int out_size, void* d_ws, size_t ws_size,
                              hipStream_t stream) {
    const float* x     = (const float*)d_in[0];
    const float* esum  = (const float*)d_in[1];
    const float* usage = (const float*)d_in[2];
    const int K = in_sizes[2];                 // 2048
    const int N = in_sizes[0] / DDIM;          // 32768

    // workspace layout
    char* p = (char*)d_ws;
    float* emb     = (float*)p;                p += (size_t)K * DDIM * 4;   // 2 MB
    float* emb_t   = (float*)p;                p += (size_t)K * DDIM * 4;   // 2 MB
    float* enorm2  = (float*)p;                p += (size_t)K * 4;
    float* pm1     = (float*)p;                p += (size_t)2 * N * 4;
    float* pm2     = (float*)p;                p += (size_t)2 * N * 4;
    int*   pi1     = (int*)p;                  p += (size_t)2 * N * 4;
    int*   codes_i = (int*)p;                  p += (size_t)N * 4;
    int*   list    = (int*)p;                  p += (size_t)N * 4;
    int*   counter = (int*)p;                  p += 256;
    u16*   xhi     = (u16*)p;                  p += (size_t)N * DDIM * 2;   // 16 MB
    u16*   ehi     = (u16*)p;                  p += (size_t)K * DDIM * 2;   // 1 MB

    float* qout    = (float*)d_out;            // N*256
    float* codes_f = qout + (size_t)N * DDIM;  // N

    prep_e<<<K, 256, 0, stream>>>(esum, usage, emb, emb_t, ehi, enorm2, counter, K);
    prep_x<<<N / 4, 256, 0, stream>>>(x, xhi);
    vq_mfma<<<(N / BM) * 2, 256, 0, stream>>>(xhi, ehi, enorm2, pm1, pi1, pm2, N);
    combine<<<N / 256, 256, 0, stream>>>(pm1, pi1, pm2, codes_f, codes_i,
                                         list, counter, N);
    rescue_c<<<512, 256, 0, stream>>>(x, emb_t, enorm2, list, counter,
                                      codes_f, codes_i, K);
    gather_q<<<N / 4, 256, 0, stream>>>(emb, codes_i, qout);
}

// Round 5
// 130.544 us; speedup vs baseline: 4.3889x; 1.3903x over previous
//
#include <hip/hip_runtime.h>

// EuclideanCodebook: fp16 MFMA approx distance (clamped) + top-2 margin flag
// + split-K batched exact fp32 rescue merged via packed atomicMin.
// x: [N=32768][256] f32, embedding_sum: [K=2048][256] f32, usage: [K] f32
// out: quantized [N*256] f32, codes [N] f32

#define EPSV 1e-5f
#define DDIM 256
#define TAU  0.4f
#define BM   128     // rows per block (vq_mfma)
#define BCL  128     // clusters per tile
#define NCT  8       // cluster tiles per half (1024/128)
#define RPB  8       // rescue rows per group
#define KSPL 4       // rescue K split

typedef __attribute__((ext_vector_type(8))) short s16x8;
typedef __attribute__((ext_vector_type(8))) _Float16 f16x8;
typedef __attribute__((ext_vector_type(4))) float f32x4;
typedef unsigned short u16;
typedef unsigned long long u64;

__device__ __forceinline__ u16 f2h(float f) {
    f = fminf(fmaxf(f, -60000.f), 60000.f);   // keep fp16 finite
    const _Float16 h = (_Float16)f;
    return __builtin_bit_cast(u16, h);
}
__device__ __forceinline__ u64 packdk(float d, int k) {
    unsigned u = __builtin_bit_cast(unsigned, d);
    u = (u & 0x80000000u) ? ~u : (u | 0x80000000u);   // sortable float
    return ((u64)u << 32) | (unsigned)k;
}

// ---------------- prep_e: emb, emb_t, e fp16, ||e||^2; zero counter ---------
__global__ void prep_e(const float* __restrict__ esum,
                       const float* __restrict__ usage,
                       float* __restrict__ emb,     // [K][256] f32
                       float* __restrict__ emb_t,   // [256][K] f32
                       u16* __restrict__ eh,        // [K][256] f16 bits
                       float* __restrict__ enorm2,  // [K]
                       int* __restrict__ counter,
                       int K) {
    if (blockIdx.x == 0 && threadIdx.x == 0) *counter = 0;
    const int k = blockIdx.x;
    const int d = threadIdx.x;                 // 256 threads
    const float u = fmaxf(usage[k], EPSV);
    const float e = esum[k * DDIM + d] / u;
    emb[k * DDIM + d] = e;
    emb_t[(size_t)d * K + k] = e;
    eh[k * DDIM + d] = f2h(e);

    float s = e * e;
    #pragma unroll
    for (int off = 32; off > 0; off >>= 1) s += __shfl_down(s, off, 64);
    __shared__ float ws[4];
    if ((threadIdx.x & 63) == 0) ws[threadIdx.x >> 6] = s;
    __syncthreads();
    if (threadIdx.x == 0) enorm2[k] = ws[0] + ws[1] + ws[2] + ws[3];
}

// ---------------- prep_x: x fp16 --------------------------------------------
__global__ void prep_x(const float* __restrict__ x, u16* __restrict__ xh) {
    const int n = blockIdx.x * 4 + (threadIdx.x >> 6);
    const int l = threadIdx.x & 63;
    const float4 v = *(const float4*)&x[(size_t)n * DDIM + l * 4];
    ushort4 h;
    h.x = f2h(v.x); h.y = f2h(v.y); h.z = f2h(v.z); h.w = f2h(v.w);
    *(ushort4*)&xh[(size_t)n * DDIM + l * 4] = h;
}

// ---------------- main: fp16 MFMA distance + running (min1, idx, min2) ------
__global__ __launch_bounds__(256, 2) void vq_mfma(
        const u16* __restrict__ xh, const u16* __restrict__ eh,
        const float* __restrict__ enorm2,
        float* __restrict__ pm1, int* __restrict__ pi1,
        float* __restrict__ pm2, int N) {
    __shared__ u16 Als[BM * 64];    // 16 KB
    __shared__ u16 Bls[BCL * 64];   // 16 KB

    const int tid = threadIdx.x;
    const int l   = tid & 63;
    const int w   = tid >> 6;            // wave 0..3
    const int wr  = w >> 1, wc = w & 1;  // 2x2 wave grid (64x64 each)
    const int rowblk = blockIdx.x >> 1;
    const int half   = blockIdx.x & 1;
    const int n0     = rowblk * BM;
    const int cbase  = half * 1024;

    float m1[4][4], m2[4][4];
    int   i1[4][4];
    #pragma unroll
    for (int a = 0; a < 4; ++a)
        #pragma unroll
        for (int b = 0; b < 4; ++b) { m1[a][b] = 3.0e38f; m2[a][b] = 3.0e38f; i1[a][b] = 0; }

    for (int ct = 0; ct < NCT; ++ct) {
        const int c0 = cbase + ct * BCL;
        f32x4 acc[4][4];
        #pragma unroll
        for (int a = 0; a < 4; ++a)
            #pragma unroll
            for (int b = 0; b < 4; ++b) acc[a][b] = (f32x4){0.f, 0.f, 0.f, 0.f};

        for (int ch = 0; ch < 4; ++ch) {       // 256 = 4 x 64 inner dims
            const int colof = ch * 64;

            __syncthreads();
            #pragma unroll
            for (int j = 0; j < 4; ++j) {
                const int r = (w * 4 + j) * 8 + (l >> 3);
                const u16* ga = xh + (size_t)(n0 + r) * DDIM + colof + (l & 7) * 8;
                __builtin_amdgcn_global_load_lds(
                    (const __attribute__((address_space(1))) void*)ga,
                    (__attribute__((address_space(3))) void*)((char*)Als + (w * 4 + j) * 1024),
                    16, 0, 0);
            }
            #pragma unroll
            for (int j = 0; j < 4; ++j) {
                const int r = (w * 4 + j) * 8 + (l >> 3);
                const u16* gb = eh + (size_t)(c0 + r) * DDIM + colof + (l & 7) * 8;
                __builtin_amdgcn_global_load_lds(
                    (const __attribute__((address_space(1))) void*)gb,
                    (__attribute__((address_space(3))) void*)((char*)Bls + (w * 4 + j) * 1024),
                    16, 0, 0);
            }
            __syncthreads();

            #pragma unroll
            for (int ks = 0; ks < 2; ++ks) {
                f16x8 af[4], bfr[4];
                #pragma unroll
                for (int f = 0; f < 4; ++f) {
                    const int arow = wr * 64 + f * 16 + (l & 15);
                    af[f] = *(const f16x8*)((const char*)Als + arow * 128 + ks * 64 + (l >> 4) * 16);
                    const int brow = wc * 64 + f * 16 + (l & 15);
                    bfr[f] = *(const f16x8*)((const char*)Bls + brow * 128 + ks * 64 + (l >> 4) * 16);
                }
                #pragma unroll
                for (int fm = 0; fm < 4; ++fm)
                    #pragma unroll
                    for (int fn = 0; fn < 4; ++fn)
                        acc[fm][fn] = __builtin_amdgcn_mfma_f32_16x16x32_f16(
                            af[fm], bfr[fn], acc[fm][fn], 0, 0, 0);
            }
        }

        // fold tile distances into running (min1, idx, min2); k ascending
        #pragma unroll
        for (int fn = 0; fn < 4; ++fn) {
            const int k = c0 + wc * 64 + fn * 16 + (l & 15);
            const float en = enorm2[k];
            #pragma unroll
            for (int fm = 0; fm < 4; ++fm)
                #pragma unroll
                for (int i = 0; i < 4; ++i) {
                    const float s = fmaf(-2.0f, acc[fm][fn][i], en);
                    const bool lt1 = s < m1[fm][i];
                    m2[fm][i] = fminf(m2[fm][i], fmaxf(s, m1[fm][i]));
                    i1[fm][i] = lt1 ? k : i1[fm][i];
                    m1[fm][i] = fminf(m1[fm][i], s);
                }
        }
    }

    // reduce across the 16 lanes (l&15) that share rows
    #pragma unroll
    for (int fm = 0; fm < 4; ++fm)
        #pragma unroll
        for (int i = 0; i < 4; ++i) {
            float a1 = m1[fm][i], a2 = m2[fm][i];
            int ai = i1[fm][i];
            #pragma unroll
            for (int mask = 1; mask < 16; mask <<= 1) {
                const float b1 = __shfl_xor(a1, mask, 64);
                const int   bi = __shfl_xor(ai, mask, 64);
                const float b2 = __shfl_xor(a2, mask, 64);
                if (b1 < a1 || (b1 == a1 && bi < ai)) {
                    a2 = fminf(a1, fminf(a2, b2)); a1 = b1; ai = bi;
                } else {
                    a2 = fminf(b1, fminf(a2, b2));
                }
            }
            m1[fm][i] = a1; i1[fm][i] = ai; m2[fm][i] = a2;
        }

    // merge the two wave-columns via LDS, write per-(half,row) partials
    __syncthreads();
    float* Sm1 = (float*)Als;
    int*   Si1 = (int*)((char*)Als + 512);
    float* Sm2 = (float*)((char*)Als + 1024);
    if (wc == 0 && (l & 15) == 0) {
        #pragma unroll
        for (int fm = 0; fm < 4; ++fm)
            #pragma unroll
            for (int i = 0; i < 4; ++i) {
                const int r = wr * 64 + fm * 16 + (l >> 4) * 4 + i;
                Sm1[r] = m1[fm][i]; Si1[r] = i1[fm][i]; Sm2[r] = m2[fm][i];
            }
    }
    __syncthreads();
    if (wc == 1 && (l & 15) == 0) {
        #pragma unroll
        for (int fm = 0; fm < 4; ++fm)
            #pragma unroll
            for (int i = 0; i < 4; ++i) {
                const int r = wr * 64 + fm * 16 + (l >> 4) * 4 + i;
                const float b1 = Sm1[r], b2 = Sm2[r];
                const int   bi = Si1[r];
                float a1 = m1[fm][i], a2 = m2[fm][i];
                int   ai = i1[fm][i];
                float M1, M2; int MI;
                if (b1 < a1 || (b1 == a1 && bi < ai)) {
                    M1 = b1; MI = bi; M2 = fminf(a1, fminf(a2, b2));
                } else {
                    M1 = a1; MI = ai; M2 = fminf(b1, fminf(a2, b2));
                }
                const int n = n0 + r;
                pm1[(size_t)half * N + n] = M1;
                pi1[(size_t)half * N + n] = MI;
                pm2[(size_t)half * N + n] = M2;
            }
    }
}

// ---------------- combine halves -> codes + flag list + packed init ---------
__global__ void combine(const float* __restrict__ pm1, const int* __restrict__ pi1,
                        const float* __restrict__ pm2,
                        float* __restrict__ codes_f, int* __restrict__ codes_i,
                        int* __restrict__ list, int* __restrict__ counter,
                        u64* __restrict__ packed, int N) {
    const int n = blockIdx.x * 256 + threadIdx.x;
    const float a1 = pm1[n], a2 = pm2[n];
    const int   ai = pi1[n];
    const float b1 = pm1[(size_t)N + n], b2 = pm2[(size_t)N + n];
    const int   bi = pi1[(size_t)N + n];
    float M1, M2; int MI;
    if (b1 < a1 || (b1 == a1 && bi < ai)) {
        M1 = b1; MI = bi; M2 = fminf(a1, fminf(a2, b2));
    } else {
        M1 = a1; MI = ai; M2 = fminf(b1, fminf(a2, b2));
    }
    codes_i[n] = MI;
    codes_f[n] = (float)MI;
    if (M2 - M1 < TAU) {
        packed[n] = 0xFFFFFFFFFFFFFFFFull;
        const int idx = atomicAdd(counter, 1);
        list[idx] = n;
    }
}

// ---------------- rescue_c: exact fp32, 8 rows x 512-cluster work items -----
// item w -> (row-group g = w/4, k-chunk q = w%4). Thread t owns clusters
// {q*512 + 2t, +1}; emb_t d-major -> coalesced float2; 16 independent fma
// chains; wave butterfly once per row; merge via packed atomicMin.
__global__ __launch_bounds__(256) void rescue_c(
        const float* __restrict__ x, const float* __restrict__ emb_t,
        const float* __restrict__ enorm2,
        const int* __restrict__ list, const int* __restrict__ counter,
        u64* __restrict__ packed, int K) {
    __shared__ float xs[RPB][DDIM];   // 8 KB
    const int t = threadIdx.x;
    const int l = t & 63;
    const int cnt = *counter;
    if (cnt == 0) return;
    const int nblk  = (cnt + RPB - 1) / RPB;
    const int items = nblk * KSPL;
    const int kc    = K / KSPL;       // 512

    for (int wi = blockIdx.x; wi < items; wi += gridDim.x) {
        const int g = wi >> 2;        // KSPL = 4
        const int q = wi & 3;
        const int base = g * RPB;
        int rows[RPB];
        #pragma unroll
        for (int r = 0; r < RPB; ++r) {
            int idx = base + r;
            rows[r] = list[idx < cnt ? idx : cnt - 1];
        }
        __syncthreads();              // previous iteration done reading xs
        #pragma unroll
        for (int r = 0; r < RPB; ++r)
            xs[r][t] = x[(size_t)rows[r] * DDIM + t];
        __syncthreads();

        float acc[RPB][2];
        #pragma unroll
        for (int r = 0; r < RPB; ++r) { acc[r][0] = 0.f; acc[r][1] = 0.f; }

        const float* eb = emb_t + q * kc + 2 * t;
        #pragma unroll 4
        for (int d = 0; d < DDIM; ++d) {
            const float2 e = *(const float2*)&eb[(size_t)d * K];
            #pragma unroll
            for (int r = 0; r < RPB; ++r) {
                const float xv = xs[r][d];
                acc[r][0] = fmaf(xv, e.x, acc[r][0]);
                acc[r][1] = fmaf(xv, e.y, acc[r][1]);
            }
        }

        const int k0 = q * kc + 2 * t;
        const float en0 = enorm2[k0], en1 = enorm2[k0 + 1];
        #pragma unroll
        for (int r = 0; r < RPB; ++r) {
            const float s0 = fmaf(-2.0f, acc[r][0], en0);
            const float s1 = fmaf(-2.0f, acc[r][1], en1);
            float bd = s0; int bk = k0;
            if (s1 < bd) { bd = s1; bk = k0 + 1; }
            #pragma unroll
            for (int m = 1; m < 64; m <<= 1) {
                const float od = __shfl_xor(bd, m, 64);
                const int   ok = __shfl_xor(bk, m, 64);
                if (od < bd || (od == bd && ok < bk)) { bd = od; bk = ok; }
            }
            if (l == 0) atomicMin(&packed[rows[r]], packdk(bd, bk));
        }
    }
}

// ---------------- fixup: unpack rescue winners into codes -------------------
__global__ void fixup(const u64* __restrict__ packed,
                      const int* __restrict__ list, const int* __restrict__ counter,
                      float* __restrict__ codes_f, int* __restrict__ codes_i) {
    const int i = blockIdx.x * 256 + threadIdx.x;
    if (i < *counter) {
        const int n = list[i];
        const int k = (int)(packed[n] & 0xFFFFFFFFull);
        codes_i[n] = k;
        codes_f[n] = (float)k;
    }
}

// ---------------- gather: quantized[n] = emb[code[n]] -----------------------
__global__ void gather_q(const float* __restrict__ emb,
                         const int* __restrict__ codes,
                         float* __restrict__ qout) {
    const int n = blockIdx.x * 4 + (threadIdx.x >> 6);
    const int c = threadIdx.x & 63;
    const int k = codes[n];
    *(float4*)&qout[(size_t)n * DDIM + c * 4] =
        *(const float4*)&emb[(size_t)k * DDIM + c * 4];
}

extern "C" void kernel_launch(void* const* d_in, const int* in_sizes, int n_in,
                              void* d_out, int out_size, void* d_ws, size_t ws_size,
                              hipStream_t stream) {
    const float* x     = (const float*)d_in[0];
    const float* esum  = (const float*)d_in[1];
    const float* usage = (const float*)d_in[2];
    const int K = in_sizes[2];                 // 2048
    const int N = in_sizes[0] / DDIM;          // 32768

    // workspace layout (packed first: 8B alignment)
    char* p = (char*)d_ws;
    u64*   packed  = (u64*)p;                  p += (size_t)N * 8;          // 256 KB
    float* emb     = (float*)p;                p += (size_t)K * DDIM * 4;   // 2 MB
    float* emb_t   = (float*)p;                p += (size_t)K * DDIM * 4;   // 2 MB
    float* enorm2  = (float*)p;                p += (size_t)K * 4;
    float* pm1     = (float*)p;                p += (size_t)2 * N * 4;
    float* pm2     = (float*)p;                p += (size_t)2 * N * 4;
    int*   pi1     = (int*)p;                  p += (size_t)2 * N * 4;
    int*   codes_i = (int*)p;                  p += (size_t)N * 4;
    int*   list    = (int*)p;                  p += (size_t)N * 4;
    int*   counter = (int*)p;                  p += 256;
    u16*   xh      = (u16*)p;                  p += (size_t)N * DDIM * 2;   // 16 MB
    u16*   eh      = (u16*)p;                  p += (size_t)K * DDIM * 2;   // 1 MB

    float* qout    = (float*)d_out;            // N*256
    float* codes_f = qout + (size_t)N * DDIM;  // N

    prep_e<<<K, 256, 0, stream>>>(esum, usage, emb, emb_t, eh, enorm2, counter, K);
    prep_x<<<N / 4, 256, 0, stream>>>(x, xh);
    vq_mfma<<<(N / BM) * 2, 256, 0, stream>>>(xh, eh, enorm2, pm1, pi1, pm2, N);
    combine<<<N / 256, 256, 0, stream>>>(pm1, pi1, pm2, codes_f, codes_i,
                                         list, counter, packed, N);
    rescue_c<<<1024, 256, 0, stream>>>(x, emb_t, enorm2, list, counter, packed, K);
    fixup<<<N / 256, 256, 0, stream>>>(packed, list, counter, codes_f, codes_i);
    gather_q<<<N / 4, 256, 0, stream>>>(emb, codes_i, qout);
}